// Round 22
// baseline (145.829 us; speedup 1.0000x reference)
//
#include <hip/hip_runtime.h>

typedef __bf16 bf16x8 __attribute__((ext_vector_type(8)));
typedef __bf16 bf16x4 __attribute__((ext_vector_type(4)));
typedef float  f32x4  __attribute__((ext_vector_type(4)));
typedef float  f32x16 __attribute__((ext_vector_type(16)));

#define TSEQ 2048
#define CDIM 1024
#define NHEAD 16
#define DH 64
#define SCALE2 0.1803368801111137f  // 0.125 * log2(e)

__device__ __forceinline__ void gl_lds16(const void* g, void* l) {
  __builtin_amdgcn_global_load_lds(
      (const __attribute__((address_space(1))) unsigned int*)g,
      (__attribute__((address_space(3))) unsigned int*)l, 16, 0, 0);
}

__device__ __forceinline__ float fexp2(float x) { return __builtin_amdgcn_exp2f(x); }

__device__ __forceinline__ unsigned cvtpk(float a, float b) {
  unsigned r;
  asm("v_cvt_pk_bf16_f32 %0, %1, %2" : "=v"(r) : "v"(a), "v"(b));
  return r;
}
__device__ __forceinline__ void permswap(unsigned& x, unsigned& y) {
  asm("v_permlane32_swap_b32 %0, %1" : "+v"(x), "+v"(y));
}

__device__ __forceinline__ float tsum16(const f32x16& s) {
  float a0 = s[0] + s[1], a1 = s[2] + s[3], a2 = s[4] + s[5], a3 = s[6] + s[7];
  float a4 = s[8] + s[9], a5 = s[10] + s[11], a6 = s[12] + s[13], a7 = s[14] + s[15];
  float b0 = a0 + a1, b1 = a2 + a3, b2 = a4 + a5, b3 = a6 + a7;
  return (b0 + b1) + (b2 + b3);
}

// ---------------- fp32 -> bf16 conversion (merged, 1 launch) ----------------
__global__ __launch_bounds__(256) void cvt_bf16_all(
    const float* __restrict__ x, const float* __restrict__ wa,
    const float* __restrict__ wp, __bf16* __restrict__ xb,
    __bf16* __restrict__ wab, __bf16* __restrict__ wpb) {
  int i = blockIdx.x * 256 + threadIdx.x;  // 0..1048575 (x8 elems)
  const float* in;
  __bf16* out;
  int off;
  if (i < 524288)      { in = x;  out = xb;  off = i; }
  else if (i < 917504) { in = wa; out = wab; off = i - 524288; }
  else                 { in = wp; out = wpb; off = i - 917504; }
  const float4* p = (const float4*)(in + (size_t)off * 8);
  float4 a = p[0], b = p[1];
  bf16x8 r;
  r[0] = (__bf16)a.x; r[1] = (__bf16)a.y; r[2] = (__bf16)a.z; r[3] = (__bf16)a.w;
  r[4] = (__bf16)b.x; r[5] = (__bf16)b.y; r[6] = (__bf16)b.z; r[7] = (__bf16)b.w;
  *(bf16x8*)(out + (size_t)off * 8) = r;
}

// ---------------- qkv GEMM 128x128 (R20 tile) + per-section orientation ---------
// Each 128-col block is pure q, k, or v. q/k: swapped mfma (feature-contiguous D,
// bf16x4 stores). v: unswapped mfma (token-contiguous D, bf16x4 v_pack stores).
__global__ __launch_bounds__(256) void gemm_qkv(
    const __bf16* __restrict__ A, const __bf16* __restrict__ Bw,
    const float* __restrict__ bias,
    __bf16* __restrict__ q_pack, __bf16* __restrict__ k_pack,
    __bf16* __restrict__ v_pack, int K) {
  __shared__ alignas(16) __bf16 lda[128 * 64];
  __shared__ alignas(16) __bf16 ldb[128 * 64];
  const int tid = threadIdx.x;
  const int lane = tid & 63, wid = tid >> 6;
  const int wm = wid >> 1, wn = wid & 1;
  const int hw = (int)(blockIdx.x + 24 * blockIdx.y);
  const int logi = (hw & 7) * 96 + (hw >> 3);
  const int row0 = (logi / 24) * 128, col0 = (logi % 24) * 128;
  const int sec = col0 >> 10;       // 0:q 1:k 2:v (block is pure-section)
  const bool isV = (sec == 2);
  f32x4 acc[4][4] = {};

  const int srow = lane >> 3;
  const int scb = ((lane & 7) ^ (lane >> 3)) * 16;

  for (int k0 = 0; k0 < K; k0 += 64) {
#pragma unroll
    for (int j = 0; j < 4; ++j) {
      int blk = j * 4 + wid;
      int r = blk * 8 + srow;
      char* la = (char*)lda + blk * 1024;
      char* lb = (char*)ldb + blk * 1024;
      gl_lds16((const char*)(A + (size_t)(row0 + r) * K + k0) + scb, la);
      gl_lds16((const char*)(Bw + (size_t)(col0 + r) * K + k0) + scb, lb);
    }
    __syncthreads();
#pragma unroll
    for (int kk = 0; kk < 2; ++kk) {
      const int sl = (((kk << 2) | (lane >> 4)) ^ (lane & 7)) * 16;
      bf16x8 af[4], bfr[4];
#pragma unroll
      for (int m = 0; m < 4; ++m)
        af[m] = *(const bf16x8*)((const char*)lda +
                                 (wm * 64 + m * 16 + (lane & 15)) * 128 + sl);
#pragma unroll
      for (int n = 0; n < 4; ++n)
        bfr[n] = *(const bf16x8*)((const char*)ldb +
                                  (wn * 64 + n * 16 + (lane & 15)) * 128 + sl);
      if (isV) {
#pragma unroll
        for (int m = 0; m < 4; ++m)
#pragma unroll
          for (int n = 0; n < 4; ++n)
            acc[m][n] = __builtin_amdgcn_mfma_f32_16x16x32_bf16(af[m], bfr[n], acc[m][n], 0, 0, 0);
      } else {
#pragma unroll
        for (int m = 0; m < 4; ++m)
#pragma unroll
          for (int n = 0; n < 4; ++n)
            acc[m][n] = __builtin_amdgcn_mfma_f32_16x16x32_bf16(bfr[n], af[m], acc[m][n], 0, 0, 0);
      }
    }
    __syncthreads();
  }

  if (isV) {
    // unswapped D: row = token (4 consecutive per thread), col = feature
#pragma unroll
    for (int m = 0; m < 4; ++m) {
      const int t0g = row0 + wm * 64 + m * 16 + (lane >> 4) * 4;
      const int bb = t0g >> 11, t0 = t0g & 2047;
      const size_t bhb = (size_t)bb * NHEAD;
#pragma unroll
      for (int n = 0; n < 4; ++n) {
        const int c = col0 + wn * 64 + n * 16 + (lane & 15);
        const int cc = c & 1023;
        const int hh = cc >> 6, d = cc & 63;
        const size_t bh = bhb + hh;
        const float bvs = bias[c];
        const int j2 = t0 >> 5, kh = (t0 >> 4) & 1, half = d >> 5;
        const int l2v = (d & 31) + ((t0 >> 3) & 1) * 32;
        const size_t idx = (bh * 256 + (size_t)(j2 * 4 + kh * 2 + half)) * 512 +
                           (size_t)l2v * 8 + (t0 & 7);
        bf16x4 w;
        w[0] = (__bf16)(acc[m][n][0] + bvs);
        w[1] = (__bf16)(acc[m][n][1] + bvs);
        w[2] = (__bf16)(acc[m][n][2] + bvs);
        w[3] = (__bf16)(acc[m][n][3] + bvs);
        *(bf16x4*)&v_pack[idx] = w;
      }
    }
  } else {
    // swapped D: row = feature (4 consecutive per thread), col = token
#pragma unroll
    for (int m = 0; m < 4; ++m) {
      const int r = row0 + wm * 64 + m * 16 + (lane & 15);  // token
      const int bb = r >> 11, t = r & 2047;
      const size_t bhb = (size_t)bb * NHEAD;
#pragma unroll
      for (int n = 0; n < 4; ++n) {
        const int c0 = col0 + wn * 64 + n * 16 + (lane >> 4) * 4;  // feature
        const int cc0 = c0 & 1023;
        const int hh = cc0 >> 6, d0 = cc0 & 63;
        const size_t bh = bhb + hh;
        const float4 bv = *(const float4*)&bias[c0];
        const int ch = t >> 5, mm = d0 >> 4;
        const int l2 = (t & 31) + ((d0 >> 3) & 1) * 32, e0 = d0 & 7;  // {0,4}
        const size_t idx = ((bh * 64 + ch) * 4 + (size_t)mm) * 512 + (size_t)l2 * 8 + e0;
        bf16x4 w;
        if (sec == 0) {
          w[0] = (__bf16)((acc[m][n][0] + bv.x) * SCALE2);
          w[1] = (__bf16)((acc[m][n][1] + bv.y) * SCALE2);
          w[2] = (__bf16)((acc[m][n][2] + bv.z) * SCALE2);
          w[3] = (__bf16)((acc[m][n][3] + bv.w) * SCALE2);
          *(bf16x4*)&q_pack[idx] = w;
        } else {
          w[0] = (__bf16)(acc[m][n][0] + bv.x);
          w[1] = (__bf16)(acc[m][n][1] + bv.y);
          w[2] = (__bf16)(acc[m][n][2] + bv.z);
          w[3] = (__bf16)(acc[m][n][3] + bv.w);
          *(bf16x4*)&k_pack[idx] = w;
        }
      }
    }
  }
}

// ---------------- proj GEMM 64x128 + T1, OPERAND-SWAPPED (float4 stores) --------
__global__ __launch_bounds__(256) void gemm_proj(
    const __bf16* __restrict__ A, const __bf16* __restrict__ Bw,
    const float* __restrict__ bias, float* __restrict__ outf) {
  const int K = CDIM, N = CDIM;
  __shared__ alignas(16) __bf16 lda[64 * 64];
  __shared__ alignas(16) __bf16 ldb[128 * 64];
  const int tid = threadIdx.x;
  const int lane = tid & 63, wid = tid >> 6;
  const int hw = (int)(blockIdx.x + 8 * blockIdx.y);  // 512 blocks, 512%8==0
  const int logi = (hw & 7) * 64 + (hw >> 3);
  const int row0 = (logi / 8) * 64, col0 = (logi % 8) * 128;
  f32x4 acc[4][2] = {};

  const int srow = lane >> 3;
  const int scb = ((lane & 7) ^ (lane >> 3)) * 16;

  for (int k0 = 0; k0 < K; k0 += 64) {
#pragma unroll
    for (int j = 0; j < 2; ++j) {
      int blk = j * 4 + wid;
      gl_lds16((const char*)(A + (size_t)(row0 + blk * 8 + srow) * K + k0) + scb,
               (char*)lda + blk * 1024);
    }
#pragma unroll
    for (int j = 0; j < 4; ++j) {
      int blk = j * 4 + wid;
      gl_lds16((const char*)(Bw + (size_t)(col0 + blk * 8 + srow) * K + k0) + scb,
               (char*)ldb + blk * 1024);
    }
    __syncthreads();
#pragma unroll
    for (int kk = 0; kk < 2; ++kk) {
      const int sl = (((kk << 2) | (lane >> 4)) ^ (lane & 7)) * 16;
      bf16x8 af[4], bfr[2];
#pragma unroll
      for (int m = 0; m < 4; ++m)
        af[m] = *(const bf16x8*)((const char*)lda + (m * 16 + (lane & 15)) * 128 + sl);
#pragma unroll
      for (int n = 0; n < 2; ++n)
        bfr[n] = *(const bf16x8*)((const char*)ldb +
                                  (wid * 32 + n * 16 + (lane & 15)) * 128 + sl);
#pragma unroll
      for (int m = 0; m < 4; ++m)
#pragma unroll
        for (int n = 0; n < 2; ++n)
          acc[m][n] = __builtin_amdgcn_mfma_f32_16x16x32_bf16(bfr[n], af[m], acc[m][n], 0, 0, 0);
    }
    __syncthreads();
  }
#pragma unroll
  for (int m = 0; m < 4; ++m) {
    const int r = row0 + m * 16 + (lane & 15);  // token
#pragma unroll
    for (int n = 0; n < 2; ++n) {
      const int c0 = col0 + wid * 32 + n * 16 + (lane >> 4) * 4;  // feature
      const float4 bv = *(const float4*)&bias[c0];
      float4 o4;
      o4.x = acc[m][n][0] + bv.x;
      o4.y = acc[m][n][1] + bv.y;
      o4.z = acc[m][n][2] + bv.z;
      o4.w = acc[m][n][3] + bv.w;
      *(float4*)&outf[(size_t)r * N + c0] = o4;
    }
  }
}

// ---------------- attention: fixed-ref softmax (R16 exact, FROZEN) ----------
__device__ __forceinline__ void softmax_pv(
    f32x16& s, bool domask, int lq, int hi,
    float& l_r, f32x16& o0, f32x16& o1,
    const bf16x8* va0, const bf16x8* va1) {
#pragma unroll
  for (int r = 0; r < 16; ++r) s[r] = fexp2(s[r]);
  if (domask) {
#pragma unroll
    for (int r = 0; r < 16; ++r) {
      int kof = (r & 3) + 8 * (r >> 2) + 4 * hi;
      if (kof > lq) s[r] = 0.f;
    }
  }
  l_r += tsum16(s);  // per-hi-half partial; cross-half shfl deferred to epilogue
  bf16x8 pb[2];
#pragma unroll
  for (int kh = 0; kh < 2; ++kh) {
    const int bq = kh * 8;
    unsigned w0 = cvtpk(s[bq + 0], s[bq + 1]);
    unsigned w1 = cvtpk(s[bq + 2], s[bq + 3]);
    unsigned w2 = cvtpk(s[bq + 4], s[bq + 5]);
    unsigned w3 = cvtpk(s[bq + 6], s[bq + 7]);
    permswap(w0, w2);
    permswap(w1, w3);
    union { unsigned u[4]; bf16x8 v; } pbu;
    pbu.u[0] = w0; pbu.u[1] = w1; pbu.u[2] = w2; pbu.u[3] = w3;
    pb[kh] = pbu.v;
  }
  o0 = __builtin_amdgcn_mfma_f32_32x32x16_bf16(va0[0], pb[0], o0, 0, 0, 0);
  o0 = __builtin_amdgcn_mfma_f32_32x32x16_bf16(va0[1], pb[1], o0, 0, 0, 0);
  o1 = __builtin_amdgcn_mfma_f32_32x32x16_bf16(va1[0], pb[0], o1, 0, 0, 0);
  o1 = __builtin_amdgcn_mfma_f32_32x32x16_bf16(va1[1], pb[1], o1, 0, 0, 0);
}

// ---------------- flash attention: paired chunks, PACKED coalesced loads ----------
__global__ __launch_bounds__(64) void attn_fwd(
    const __bf16* __restrict__ q_pack, const __bf16* __restrict__ k_pack,
    const __bf16* __restrict__ v_pack, __bf16* __restrict__ y_buf) {
  const int lane = threadIdx.x;
  const int lq = lane & 31;
  const int hi = lane >> 5;
  const int bh = blockIdx.x;
  const int wv = blockIdx.y;          // wv=0 (64-iter block) dispatched first
  const int b = bh >> 4, h = bh & 15;
  const int cH = 63 - wv, cL = wv;
  const float slope2 = exp2f(-0.5f * (float)(h + 1)) * 1.44269504f;
  const __bf16* qpk = q_pack + (size_t)bh * 64 * 2048;
  const __bf16* kpk = k_pack + (size_t)bh * 64 * 2048;
  const __bf16* vpk = v_pack + (size_t)bh * 64 * 2048;
  const int lo = lane * 8;  // elem offset inside each 512-elem fragment block

  bf16x8 qfH[4], qfL[4];
#pragma unroll
  for (int m = 0; m < 4; ++m) {
    qfH[m] = *(const bf16x8*)&qpk[(size_t)(cH * 4 + m) * 512 + lo];
    qfL[m] = *(const bf16x8*)&qpk[(size_t)(cL * 4 + m) * 512 + lo];
  }
  float pk_[16];
#pragma unroll
  for (int r = 0; r < 16; ++r)
    pk_[r] = slope2 * (float)((r & 3) + 8 * (r >> 2) + 4 * hi);

  f32x16 oH0 = {}, oH1 = {}, oL0 = {}, oL1 = {};
  float lH = 0.f, lL = 0.f;

  bf16x8 kf[4];
#pragma unroll
  for (int m = 0; m < 4; ++m)
    kf[m] = *(const bf16x8*)&kpk[(size_t)m * 512 + lo];

  for (int j = 0; j <= cH; ++j) {
    const int kt = j * 32;
    bf16x8 va0[2], va1[2];
#pragma unroll
    for (int kh = 0; kh < 2; ++kh) {
      va0[kh] = *(const bf16x8*)&vpk[(size_t)(j * 4 + kh * 2 + 0) * 512 + lo];
      va1[kh] = *(const bf16x8*)&vpk[(size_t)(j * 4 + kh * 2 + 1) * 512 + lo];
    }
    bf16x8 kn[4];
    const bool pre = (j < cH);
    if (pre) {
#pragma unroll
      for (int m = 0; m < 4; ++m)
        kn[m] = *(const bf16x8*)&kpk[(size_t)((j + 1) * 4 + m) * 512 + lo];
    }
    // bias as MFMA C-init: s starts at pk_ + slope2*(kt - q0)
    const float bH = slope2 * (float)(kt - cH * 32);
    f32x16 sH;
#pragma unroll
    for (int r = 0; r < 16; ++r) sH[r] = pk_[r] + bH;
#pragma unroll
    for (int m = 0; m < 4; ++m)
      sH = __builtin_amdgcn_mfma_f32_32x32x16_bf16(kf[m], qfH[m], sH, 0, 0, 0);
    const bool lact = (j <= cL);
    f32x16 sL;
    if (lact) {
      const float bL = slope2 * (float)(kt - cL * 32);
#pragma unroll
      for (int r = 0; r < 16; ++r) sL[r] = pk_[r] + bL;
#pragma unroll
      for (int m = 0; m < 4; ++m)
        sL = __builtin_amdgcn_mfma_f32_32x32x16_bf16(kf[m], qfL[m], sL, 0, 0, 0);
    }
    softmax_pv(sH, j == cH, lq, hi, lH, oH0, oH1, va0, va1);
    if (lact)
      softmax_pv(sL, j == cL, lq, hi, lL, oL0, oL1, va0, va1);
    if (pre) {
#pragma unroll
      for (int m = 0; m < 4; ++m) kf[m] = kn[m];
    }
  }
  // deferred cross-half l reduction (once)
  lH += __shfl_xor(lH, 32, 64);
  lL += __shfl_xor(lL, 32, 64);

  // normalized direct write: lane owns q-row t = c*32+lq; d = 8g+4hi+e (+32 for o1)
#pragma unroll
  for (int g2 = 0; g2 < 2; ++g2) {
    const int c = g2 ? cL : cH;
    const f32x16& a0 = g2 ? oL0 : oH0;
    const f32x16& a1 = g2 ? oL1 : oH1;
    const float inv = 1.0f / (g2 ? lL : lH);
    __bf16* yb = y_buf + ((size_t)b * TSEQ + c * 32 + lq) * CDIM + h * DH;
#pragma unroll
    for (int g = 0; g < 4; ++g) {
      bf16x4 v0, v1;
#pragma unroll
      for (int e = 0; e < 4; ++e) {
        v0[e] = (__bf16)(a0[4 * g + e] * inv);
        v1[e] = (__bf16)(a1[4 * g + e] * inv);
      }
      *(bf16x4*)&yb[8 * g + 4 * hi] = v0;
      *(bf16x4*)&yb[32 + 8 * g + 4 * hi] = v1;
    }
  }
}

extern "C" void kernel_launch(void* const* d_in, const int* in_sizes, int n_in,
                              void* d_out, int out_size, void* d_ws, size_t ws_size,
                              hipStream_t stream) {
  const float* x      = (const float*)d_in[0];
  const float* W_attn = (const float*)d_in[1];
  const float* b_attn = (const float*)d_in[2];
  const float* W_proj = (const float*)d_in[3];
  const float* b_proj = (const float*)d_in[4];
  float* out = (float*)d_out;
  char* ws = (char*)d_ws;
  const size_t MB = (size_t)1 << 20;
  __bf16* xb  = (__bf16*)(ws + 0 * MB);
  __bf16* wab = (__bf16*)(ws + 8 * MB);
  __bf16* wpb = (__bf16*)(ws + 14 * MB);
  __bf16* qpk = (__bf16*)(ws + 16 * MB);  // 8 MB packed Q frags
  __bf16* kpk = (__bf16*)(ws + 24 * MB);  // 8 MB packed K frags
  __bf16* vpk = (__bf16*)(ws + 32 * MB);  // 8 MB packed V frags
  __bf16* yb  = (__bf16*)(ws + 40 * MB);

  cvt_bf16_all<<<4096, 256, 0, stream>>>(x, W_attn, W_proj, xb, wab, wpb);

  gemm_qkv<<<dim3(24, 32), 256, 0, stream>>>(xb, wab, b_attn, qpk, kpk, vpk, 1024);
  attn_fwd<<<dim3(32, 32), 64, 0, stream>>>(qpk, kpk, vpk, yb);
  gemm_proj<<<dim3(8, 64), 256, 0, stream>>>(yb, wpb, b_proj, out);
}

// Round 23
// 108.102 us; speedup vs baseline: 1.3490x; 1.3490x over previous
//
#include <hip/hip_runtime.h>

typedef __bf16 bf16x8 __attribute__((ext_vector_type(8)));
typedef __bf16 bf16x4 __attribute__((ext_vector_type(4)));
typedef float  f32x4  __attribute__((ext_vector_type(4)));
typedef float  f32x16 __attribute__((ext_vector_type(16)));

#define TSEQ 2048
#define CDIM 1024
#define NHEAD 16
#define DH 64
#define SCALE2 0.1803368801111137f  // 0.125 * log2(e)

__device__ __forceinline__ void gl_lds16(const void* g, void* l) {
  __builtin_amdgcn_global_load_lds(
      (const __attribute__((address_space(1))) unsigned int*)g,
      (__attribute__((address_space(3))) unsigned int*)l, 16, 0, 0);
}

__device__ __forceinline__ float fexp2(float x) { return __builtin_amdgcn_exp2f(x); }

__device__ __forceinline__ unsigned cvtpk(float a, float b) {
  unsigned r;
  asm("v_cvt_pk_bf16_f32 %0, %1, %2" : "=v"(r) : "v"(a), "v"(b));
  return r;
}
__device__ __forceinline__ void permswap(unsigned& x, unsigned& y) {
  asm("v_permlane32_swap_b32 %0, %1" : "+v"(x), "+v"(y));
}

__device__ __forceinline__ float tsum16(const f32x16& s) {
  float a0 = s[0] + s[1], a1 = s[2] + s[3], a2 = s[4] + s[5], a3 = s[6] + s[7];
  float a4 = s[8] + s[9], a5 = s[10] + s[11], a6 = s[12] + s[13], a7 = s[14] + s[15];
  float b0 = a0 + a1, b1 = a2 + a3, b2 = a4 + a5, b3 = a6 + a7;
  return (b0 + b1) + (b2 + b3);
}

// ---------------- fp32 -> bf16 conversion (merged, 1 launch) ----------------
__global__ __launch_bounds__(256) void cvt_bf16_all(
    const float* __restrict__ x, const float* __restrict__ wa,
    const float* __restrict__ wp, __bf16* __restrict__ xb,
    __bf16* __restrict__ wab, __bf16* __restrict__ wpb) {
  int i = blockIdx.x * 256 + threadIdx.x;  // 0..1048575 (x8 elems)
  const float* in;
  __bf16* out;
  int off;
  if (i < 524288)      { in = x;  out = xb;  off = i; }
  else if (i < 917504) { in = wa; out = wab; off = i - 524288; }
  else                 { in = wp; out = wpb; off = i - 917504; }
  const float4* p = (const float4*)(in + (size_t)off * 8);
  float4 a = p[0], b = p[1];
  bf16x8 r;
  r[0] = (__bf16)a.x; r[1] = (__bf16)a.y; r[2] = (__bf16)a.z; r[3] = (__bf16)a.w;
  r[4] = (__bf16)b.x; r[5] = (__bf16)b.y; r[6] = (__bf16)b.z; r[7] = (__bf16)b.w;
  *(bf16x8*)(out + (size_t)off * 8) = r;
}

// ---------------- bf16 GEMM 128x128 (m97 + T2 + T1), OPERAND-SWAPPED (R20) -------
// mfma(B_frag, A_frag): D row = feature (4 consecutive per thread), col = token.
// q/k epilogue becomes bf16x4 stores (16 instead of 64 per thread), float4 bias.
__global__ __launch_bounds__(256) void gemm_qkv(
    const __bf16* __restrict__ A, const __bf16* __restrict__ Bw,
    const float* __restrict__ bias,
    __bf16* __restrict__ q_pack, __bf16* __restrict__ k_pack,
    __bf16* __restrict__ v_pack, int K) {
  __shared__ alignas(16) __bf16 lda[128 * 64];
  __shared__ alignas(16) __bf16 ldb[128 * 64];
  const int tid = threadIdx.x;
  const int lane = tid & 63, wid = tid >> 6;
  const int wm = wid >> 1, wn = wid & 1;
  const int hw = (int)(blockIdx.x + 24 * blockIdx.y);
  const int logi = (hw & 7) * 96 + (hw >> 3);
  const int row0 = (logi / 24) * 128, col0 = (logi % 24) * 128;
  f32x4 acc[4][4] = {};

  const int srow = lane >> 3;
  const int scb = ((lane & 7) ^ (lane >> 3)) * 16;

  for (int k0 = 0; k0 < K; k0 += 64) {
#pragma unroll
    for (int j = 0; j < 4; ++j) {
      int blk = j * 4 + wid;
      int r = blk * 8 + srow;
      char* la = (char*)lda + blk * 1024;
      char* lb = (char*)ldb + blk * 1024;
      gl_lds16((const char*)(A + (size_t)(row0 + r) * K + k0) + scb, la);
      gl_lds16((const char*)(Bw + (size_t)(col0 + r) * K + k0) + scb, lb);
    }
    __syncthreads();
#pragma unroll
    for (int kk = 0; kk < 2; ++kk) {
      const int sl = (((kk << 2) | (lane >> 4)) ^ (lane & 7)) * 16;
      bf16x8 af[4], bfr[4];
#pragma unroll
      for (int m = 0; m < 4; ++m)
        af[m] = *(const bf16x8*)((const char*)lda +
                                 (wm * 64 + m * 16 + (lane & 15)) * 128 + sl);
#pragma unroll
      for (int n = 0; n < 4; ++n)
        bfr[n] = *(const bf16x8*)((const char*)ldb +
                                  (wn * 64 + n * 16 + (lane & 15)) * 128 + sl);
#pragma unroll
      for (int m = 0; m < 4; ++m)
#pragma unroll
        for (int n = 0; n < 4; ++n)
          acc[m][n] = __builtin_amdgcn_mfma_f32_16x16x32_bf16(bfr[n], af[m], acc[m][n], 0, 0, 0);
    }
    __syncthreads();
  }
  // epilogue (swapped D): row=(lane>>4)*4+i = feature, col=lane&15 = token
#pragma unroll
  for (int m = 0; m < 4; ++m) {
    const int r = row0 + wm * 64 + m * 16 + (lane & 15);  // token
    const int bb = r >> 11, t = r & 2047;
    const size_t bhb = (size_t)bb * NHEAD;
#pragma unroll
    for (int n = 0; n < 4; ++n) {
      const int c0 = col0 + wn * 64 + n * 16 + (lane >> 4) * 4;  // feature (4 consec)
      const int sec = c0 >> 10;
      const int cc0 = c0 & 1023;
      const int hh = cc0 >> 6, d0 = cc0 & 63;
      const size_t bh = bhb + hh;
      const float4 bv = *(const float4*)&bias[c0];
      const float v0 = acc[m][n][0] + bv.x;
      const float v1 = acc[m][n][1] + bv.y;
      const float v2 = acc[m][n][2] + bv.z;
      const float v3 = acc[m][n][3] + bv.w;
      if (sec == 2) {
        const int j2 = t >> 5, kh = (t >> 4) & 1, half = d0 >> 5;
        const size_t base = (bh * 256 + (size_t)(j2 * 4 + kh * 2 + half)) * 512 + (size_t)(t & 7);
        const int l2v0 = (d0 & 31) + ((t >> 3) & 1) * 32;
        v_pack[base + (size_t)(l2v0 + 0) * 8] = (__bf16)v0;
        v_pack[base + (size_t)(l2v0 + 1) * 8] = (__bf16)v1;
        v_pack[base + (size_t)(l2v0 + 2) * 8] = (__bf16)v2;
        v_pack[base + (size_t)(l2v0 + 3) * 8] = (__bf16)v3;
      } else {
        const int ch = t >> 5, mm = d0 >> 4;
        const int l2 = (t & 31) + ((d0 >> 3) & 1) * 32, e0 = d0 & 7;  // e0 in {0,4}
        const size_t idx = ((bh * 64 + ch) * 4 + (size_t)mm) * 512 + (size_t)l2 * 8 + e0;
        bf16x4 w;
        if (sec == 0) {
          w[0] = (__bf16)(v0 * SCALE2); w[1] = (__bf16)(v1 * SCALE2);
          w[2] = (__bf16)(v2 * SCALE2); w[3] = (__bf16)(v3 * SCALE2);
          *(bf16x4*)&q_pack[idx] = w;
        } else {
          w[0] = (__bf16)v0; w[1] = (__bf16)v1; w[2] = (__bf16)v2; w[3] = (__bf16)v3;
          *(bf16x4*)&k_pack[idx] = w;
        }
      }
    }
  }
}

// ---------------- proj GEMM 64x128 + T1, OPERAND-SWAPPED (float4 stores) --------
__global__ __launch_bounds__(256) void gemm_proj(
    const __bf16* __restrict__ A, const __bf16* __restrict__ Bw,
    const float* __restrict__ bias, float* __restrict__ outf) {
  const int K = CDIM, N = CDIM;
  __shared__ alignas(16) __bf16 lda[64 * 64];
  __shared__ alignas(16) __bf16 ldb[128 * 64];
  const int tid = threadIdx.x;
  const int lane = tid & 63, wid = tid >> 6;
  const int hw = (int)(blockIdx.x + 8 * blockIdx.y);  // 512 blocks, 512%8==0
  const int logi = (hw & 7) * 64 + (hw >> 3);
  const int row0 = (logi / 8) * 64, col0 = (logi % 8) * 128;
  f32x4 acc[4][2] = {};

  const int srow = lane >> 3;
  const int scb = ((lane & 7) ^ (lane >> 3)) * 16;

  for (int k0 = 0; k0 < K; k0 += 64) {
#pragma unroll
    for (int j = 0; j < 2; ++j) {
      int blk = j * 4 + wid;
      gl_lds16((const char*)(A + (size_t)(row0 + blk * 8 + srow) * K + k0) + scb,
               (char*)lda + blk * 1024);
    }
#pragma unroll
    for (int j = 0; j < 4; ++j) {
      int blk = j * 4 + wid;
      gl_lds16((const char*)(Bw + (size_t)(col0 + blk * 8 + srow) * K + k0) + scb,
               (char*)ldb + blk * 1024);
    }
    __syncthreads();
#pragma unroll
    for (int kk = 0; kk < 2; ++kk) {
      const int sl = (((kk << 2) | (lane >> 4)) ^ (lane & 7)) * 16;
      bf16x8 af[4], bfr[2];
#pragma unroll
      for (int m = 0; m < 4; ++m)
        af[m] = *(const bf16x8*)((const char*)lda + (m * 16 + (lane & 15)) * 128 + sl);
#pragma unroll
      for (int n = 0; n < 2; ++n)
        bfr[n] = *(const bf16x8*)((const char*)ldb +
                                  (wid * 32 + n * 16 + (lane & 15)) * 128 + sl);
#pragma unroll
      for (int m = 0; m < 4; ++m)
#pragma unroll
        for (int n = 0; n < 2; ++n)
          acc[m][n] = __builtin_amdgcn_mfma_f32_16x16x32_bf16(bfr[n], af[m], acc[m][n], 0, 0, 0);
    }
    __syncthreads();
  }
  // swapped D: thread owns 4 consecutive output features of one token -> float4
#pragma unroll
  for (int m = 0; m < 4; ++m) {
    const int r = row0 + m * 16 + (lane & 15);  // token
#pragma unroll
    for (int n = 0; n < 2; ++n) {
      const int c0 = col0 + wid * 32 + n * 16 + (lane >> 4) * 4;  // feature
      const float4 bv = *(const float4*)&bias[c0];
      float4 o4;
      o4.x = acc[m][n][0] + bv.x;
      o4.y = acc[m][n][1] + bv.y;
      o4.z = acc[m][n][2] + bv.z;
      o4.w = acc[m][n][3] + bv.w;
      *(float4*)&outf[(size_t)r * N + c0] = o4;
    }
  }
}

// ---------------- attention: fixed-ref softmax (R16 exact, FROZEN) ----------
__device__ __forceinline__ void softmax_pv(
    f32x16& s, bool domask, int lq, int hi,
    float& l_r, f32x16& o0, f32x16& o1,
    const bf16x8* va0, const bf16x8* va1) {
#pragma unroll
  for (int r = 0; r < 16; ++r) s[r] = fexp2(s[r]);
  if (domask) {
#pragma unroll
    for (int r = 0; r < 16; ++r) {
      int kof = (r & 3) + 8 * (r >> 2) + 4 * hi;
      if (kof > lq) s[r] = 0.f;
    }
  }
  l_r += tsum16(s);  // per-hi-half partial; cross-half shfl deferred to epilogue
  bf16x8 pb[2];
#pragma unroll
  for (int kh = 0; kh < 2; ++kh) {
    const int bq = kh * 8;
    unsigned w0 = cvtpk(s[bq + 0], s[bq + 1]);
    unsigned w1 = cvtpk(s[bq + 2], s[bq + 3]);
    unsigned w2 = cvtpk(s[bq + 4], s[bq + 5]);
    unsigned w3 = cvtpk(s[bq + 6], s[bq + 7]);
    permswap(w0, w2);
    permswap(w1, w3);
    union { unsigned u[4]; bf16x8 v; } pbu;
    pbu.u[0] = w0; pbu.u[1] = w1; pbu.u[2] = w2; pbu.u[3] = w3;
    pb[kh] = pbu.v;
  }
  o0 = __builtin_amdgcn_mfma_f32_32x32x16_bf16(va0[0], pb[0], o0, 0, 0, 0);
  o0 = __builtin_amdgcn_mfma_f32_32x32x16_bf16(va0[1], pb[1], o0, 0, 0, 0);
  o1 = __builtin_amdgcn_mfma_f32_32x32x16_bf16(va1[0], pb[0], o1, 0, 0, 0);
  o1 = __builtin_amdgcn_mfma_f32_32x32x16_bf16(va1[1], pb[1], o1, 0, 0, 0);
}

// ---------------- flash attention: paired chunks, PACKED coalesced loads ----------
__global__ __launch_bounds__(64) void attn_fwd(
    const __bf16* __restrict__ q_pack, const __bf16* __restrict__ k_pack,
    const __bf16* __restrict__ v_pack, __bf16* __restrict__ y_buf) {
  const int lane = threadIdx.x;
  const int lq = lane & 31;
  const int hi = lane >> 5;
  const int bh = blockIdx.x;
  const int wv = blockIdx.y;          // wv=0 (64-iter block) dispatched first
  const int b = bh >> 4, h = bh & 15;
  const int cH = 63 - wv, cL = wv;
  const float slope2 = exp2f(-0.5f * (float)(h + 1)) * 1.44269504f;
  const __bf16* qpk = q_pack + (size_t)bh * 64 * 2048;
  const __bf16* kpk = k_pack + (size_t)bh * 64 * 2048;
  const __bf16* vpk = v_pack + (size_t)bh * 64 * 2048;
  const int lo = lane * 8;  // elem offset inside each 512-elem fragment block

  bf16x8 qfH[4], qfL[4];
#pragma unroll
  for (int m = 0; m < 4; ++m) {
    qfH[m] = *(const bf16x8*)&qpk[(size_t)(cH * 4 + m) * 512 + lo];
    qfL[m] = *(const bf16x8*)&qpk[(size_t)(cL * 4 + m) * 512 + lo];
  }
  float pk_[16];
#pragma unroll
  for (int r = 0; r < 16; ++r)
    pk_[r] = slope2 * (float)((r & 3) + 8 * (r >> 2) + 4 * hi);

  f32x16 oH0 = {}, oH1 = {}, oL0 = {}, oL1 = {};
  float lH = 0.f, lL = 0.f;

  bf16x8 kf[4];
#pragma unroll
  for (int m = 0; m < 4; ++m)
    kf[m] = *(const bf16x8*)&kpk[(size_t)m * 512 + lo];

  for (int j = 0; j <= cH; ++j) {
    const int kt = j * 32;
    bf16x8 va0[2], va1[2];
#pragma unroll
    for (int kh = 0; kh < 2; ++kh) {
      va0[kh] = *(const bf16x8*)&vpk[(size_t)(j * 4 + kh * 2 + 0) * 512 + lo];
      va1[kh] = *(const bf16x8*)&vpk[(size_t)(j * 4 + kh * 2 + 1) * 512 + lo];
    }
    bf16x8 kn[4];
    const bool pre = (j < cH);
    if (pre) {
#pragma unroll
      for (int m = 0; m < 4; ++m)
        kn[m] = *(const bf16x8*)&kpk[(size_t)((j + 1) * 4 + m) * 512 + lo];
    }
    // bias as MFMA C-init: s starts at pk_ + slope2*(kt - q0)
    const float bH = slope2 * (float)(kt - cH * 32);
    f32x16 sH;
#pragma unroll
    for (int r = 0; r < 16; ++r) sH[r] = pk_[r] + bH;
#pragma unroll
    for (int m = 0; m < 4; ++m)
      sH = __builtin_amdgcn_mfma_f32_32x32x16_bf16(kf[m], qfH[m], sH, 0, 0, 0);
    const bool lact = (j <= cL);
    f32x16 sL;
    if (lact) {
      const float bL = slope2 * (float)(kt - cL * 32);
#pragma unroll
      for (int r = 0; r < 16; ++r) sL[r] = pk_[r] + bL;
#pragma unroll
      for (int m = 0; m < 4; ++m)
        sL = __builtin_amdgcn_mfma_f32_32x32x16_bf16(kf[m], qfL[m], sL, 0, 0, 0);
    }
    softmax_pv(sH, j == cH, lq, hi, lH, oH0, oH1, va0, va1);
    if (lact)
      softmax_pv(sL, j == cL, lq, hi, lL, oL0, oL1, va0, va1);
    if (pre) {
#pragma unroll
      for (int m = 0; m < 4; ++m) kf[m] = kn[m];
    }
  }
  // deferred cross-half l reduction (once)
  lH += __shfl_xor(lH, 32, 64);
  lL += __shfl_xor(lL, 32, 64);

  // normalized direct write: lane owns q-row t = c*32+lq; d = 8g+4hi+e (+32 for o1)
#pragma unroll
  for (int g2 = 0; g2 < 2; ++g2) {
    const int c = g2 ? cL : cH;
    const f32x16& a0 = g2 ? oL0 : oH0;
    const f32x16& a1 = g2 ? oL1 : oH1;
    const float inv = 1.0f / (g2 ? lL : lH);
    __bf16* yb = y_buf + ((size_t)b * TSEQ + c * 32 + lq) * CDIM + h * DH;
#pragma unroll
    for (int g = 0; g < 4; ++g) {
      bf16x4 v0, v1;
#pragma unroll
      for (int e = 0; e < 4; ++e) {
        v0[e] = (__bf16)(a0[4 * g + e] * inv);
        v1[e] = (__bf16)(a1[4 * g + e] * inv);
      }
      *(bf16x4*)&yb[8 * g + 4 * hi] = v0;
      *(bf16x4*)&yb[32 + 8 * g + 4 * hi] = v1;
    }
  }
}

extern "C" void kernel_launch(void* const* d_in, const int* in_sizes, int n_in,
                              void* d_out, int out_size, void* d_ws, size_t ws_size,
                              hipStream_t stream) {
  const float* x      = (const float*)d_in[0];
  const float* W_attn = (const float*)d_in[1];
  const float* b_attn = (const float*)d_in[2];
  const float* W_proj = (const float*)d_in[3];
  const float* b_proj = (const float*)d_in[4];
  float* out = (float*)d_out;
  char* ws = (char*)d_ws;
  const size_t MB = (size_t)1 << 20;
  __bf16* xb  = (__bf16*)(ws + 0 * MB);
  __bf16* wab = (__bf16*)(ws + 8 * MB);
  __bf16* wpb = (__bf16*)(ws + 14 * MB);
  __bf16* qpk = (__bf16*)(ws + 16 * MB);  // 8 MB packed Q frags
  __bf16* kpk = (__bf16*)(ws + 24 * MB);  // 8 MB packed K frags
  __bf16* vpk = (__bf16*)(ws + 32 * MB);  // 8 MB packed V frags
  __bf16* yb  = (__bf16*)(ws + 40 * MB);

  cvt_bf16_all<<<4096, 256, 0, stream>>>(x, W_attn, W_proj, xb, wab, wpb);

  gemm_qkv<<<dim3(24, 32), 256, 0, stream>>>(xb, wab, b_attn, qpk, kpk, vpk, 1024);
  attn_fwd<<<dim3(32, 32), 64, 0, stream>>>(qpk, kpk, vpk, yb);
  gemm_proj<<<dim3(8, 64), 256, 0, stream>>>(yb, wpb, b_proj, out);
}

// Round 24
// 107.987 us; speedup vs baseline: 1.3504x; 1.0011x over previous
//
#include <hip/hip_runtime.h>

typedef __bf16 bf16x8 __attribute__((ext_vector_type(8)));
typedef __bf16 bf16x4 __attribute__((ext_vector_type(4)));
typedef float  f32x4  __attribute__((ext_vector_type(4)));
typedef float  f32x16 __attribute__((ext_vector_type(16)));

#define TSEQ 2048
#define CDIM 1024
#define NHEAD 16
#define DH 64
#define SCALE2 0.1803368801111137f  // 0.125 * log2(e)

__device__ __forceinline__ void gl_lds16(const void* g, void* l) {
  __builtin_amdgcn_global_load_lds(
      (const __attribute__((address_space(1))) unsigned int*)g,
      (__attribute__((address_space(3))) unsigned int*)l, 16, 0, 0);
}

__device__ __forceinline__ float fexp2(float x) { return __builtin_amdgcn_exp2f(x); }

__device__ __forceinline__ unsigned cvtpk(float a, float b) {
  unsigned r;
  asm("v_cvt_pk_bf16_f32 %0, %1, %2" : "=v"(r) : "v"(a), "v"(b));
  return r;
}
__device__ __forceinline__ void permswap(unsigned& x, unsigned& y) {
  asm("v_permlane32_swap_b32 %0, %1" : "+v"(x), "+v"(y));
}

__device__ __forceinline__ float tsum16(const f32x16& s) {
  float a0 = s[0] + s[1], a1 = s[2] + s[3], a2 = s[4] + s[5], a3 = s[6] + s[7];
  float a4 = s[8] + s[9], a5 = s[10] + s[11], a6 = s[12] + s[13], a7 = s[14] + s[15];
  float b0 = a0 + a1, b1 = a2 + a3, b2 = a4 + a5, b3 = a6 + a7;
  return (b0 + b1) + (b2 + b3);
}

// ---------------- fp32 -> bf16 conversion (merged, 1 launch) ----------------
__global__ __launch_bounds__(256) void cvt_bf16_all(
    const float* __restrict__ x, const float* __restrict__ wa,
    const float* __restrict__ wp, __bf16* __restrict__ xb,
    __bf16* __restrict__ wab, __bf16* __restrict__ wpb) {
  int i = blockIdx.x * 256 + threadIdx.x;  // 0..1048575 (x8 elems)
  const float* in;
  __bf16* out;
  int off;
  if (i < 524288)      { in = x;  out = xb;  off = i; }
  else if (i < 917504) { in = wa; out = wab; off = i - 524288; }
  else                 { in = wp; out = wpb; off = i - 917504; }
  const float4* p = (const float4*)(in + (size_t)off * 8);
  float4 a = p[0], b = p[1];
  bf16x8 r;
  r[0] = (__bf16)a.x; r[1] = (__bf16)a.y; r[2] = (__bf16)a.z; r[3] = (__bf16)a.w;
  r[4] = (__bf16)b.x; r[5] = (__bf16)b.y; r[6] = (__bf16)b.z; r[7] = (__bf16)b.w;
  *(bf16x8*)(out + (size_t)off * 8) = r;
}

// ---------------- bf16 GEMM 128x128 (m97 + T2 + T1), OPERAND-SWAPPED -------------
// mfma(B_frag, A_frag): D row = feature (4 consecutive per thread), col = token.
// q/k epilogue: bf16x4 stores + float4 bias; v: scalar scatter (measured cheapest).
__global__ __launch_bounds__(256) void gemm_qkv(
    const __bf16* __restrict__ A, const __bf16* __restrict__ Bw,
    const float* __restrict__ bias,
    __bf16* __restrict__ q_pack, __bf16* __restrict__ k_pack,
    __bf16* __restrict__ v_pack, int K) {
  __shared__ alignas(16) __bf16 lda[128 * 64];
  __shared__ alignas(16) __bf16 ldb[128 * 64];
  const int tid = threadIdx.x;
  const int lane = tid & 63, wid = tid >> 6;
  const int wm = wid >> 1, wn = wid & 1;
  const int hw = (int)(blockIdx.x + 24 * blockIdx.y);
  const int logi = (hw & 7) * 96 + (hw >> 3);
  const int row0 = (logi / 24) * 128, col0 = (logi % 24) * 128;
  f32x4 acc[4][4] = {};

  const int srow = lane >> 3;
  const int scb = ((lane & 7) ^ (lane >> 3)) * 16;

  for (int k0 = 0; k0 < K; k0 += 64) {
#pragma unroll
    for (int j = 0; j < 4; ++j) {
      int blk = j * 4 + wid;
      int r = blk * 8 + srow;
      char* la = (char*)lda + blk * 1024;
      char* lb = (char*)ldb + blk * 1024;
      gl_lds16((const char*)(A + (size_t)(row0 + r) * K + k0) + scb, la);
      gl_lds16((const char*)(Bw + (size_t)(col0 + r) * K + k0) + scb, lb);
    }
    __syncthreads();
#pragma unroll
    for (int kk = 0; kk < 2; ++kk) {
      const int sl = (((kk << 2) | (lane >> 4)) ^ (lane & 7)) * 16;
      bf16x8 af[4], bfr[4];
#pragma unroll
      for (int m = 0; m < 4; ++m)
        af[m] = *(const bf16x8*)((const char*)lda +
                                 (wm * 64 + m * 16 + (lane & 15)) * 128 + sl);
#pragma unroll
      for (int n = 0; n < 4; ++n)
        bfr[n] = *(const bf16x8*)((const char*)ldb +
                                  (wn * 64 + n * 16 + (lane & 15)) * 128 + sl);
#pragma unroll
      for (int m = 0; m < 4; ++m)
#pragma unroll
        for (int n = 0; n < 4; ++n)
          acc[m][n] = __builtin_amdgcn_mfma_f32_16x16x32_bf16(bfr[n], af[m], acc[m][n], 0, 0, 0);
    }
    __syncthreads();
  }
  // epilogue (swapped D): row=(lane>>4)*4+i = feature, col=lane&15 = token
#pragma unroll
  for (int m = 0; m < 4; ++m) {
    const int r = row0 + wm * 64 + m * 16 + (lane & 15);  // token
    const int bb = r >> 11, t = r & 2047;
    const size_t bhb = (size_t)bb * NHEAD;
#pragma unroll
    for (int n = 0; n < 4; ++n) {
      const int c0 = col0 + wn * 64 + n * 16 + (lane >> 4) * 4;  // feature (4 consec)
      const int sec = c0 >> 10;
      const int cc0 = c0 & 1023;
      const int hh = cc0 >> 6, d0 = cc0 & 63;
      const size_t bh = bhb + hh;
      const float4 bv = *(const float4*)&bias[c0];
      const float v0 = acc[m][n][0] + bv.x;
      const float v1 = acc[m][n][1] + bv.y;
      const float v2 = acc[m][n][2] + bv.z;
      const float v3 = acc[m][n][3] + bv.w;
      if (sec == 2) {
        const int j2 = t >> 5, kh = (t >> 4) & 1, half = d0 >> 5;
        const size_t base = (bh * 256 + (size_t)(j2 * 4 + kh * 2 + half)) * 512 + (size_t)(t & 7);
        const int l2v0 = (d0 & 31) + ((t >> 3) & 1) * 32;
        v_pack[base + (size_t)(l2v0 + 0) * 8] = (__bf16)v0;
        v_pack[base + (size_t)(l2v0 + 1) * 8] = (__bf16)v1;
        v_pack[base + (size_t)(l2v0 + 2) * 8] = (__bf16)v2;
        v_pack[base + (size_t)(l2v0 + 3) * 8] = (__bf16)v3;
      } else {
        const int ch = t >> 5, mm = d0 >> 4;
        const int l2 = (t & 31) + ((d0 >> 3) & 1) * 32, e0 = d0 & 7;  // e0 in {0,4}
        const size_t idx = ((bh * 64 + ch) * 4 + (size_t)mm) * 512 + (size_t)l2 * 8 + e0;
        bf16x4 w;
        if (sec == 0) {
          w[0] = (__bf16)(v0 * SCALE2); w[1] = (__bf16)(v1 * SCALE2);
          w[2] = (__bf16)(v2 * SCALE2); w[3] = (__bf16)(v3 * SCALE2);
          *(bf16x4*)&q_pack[idx] = w;
        } else {
          w[0] = (__bf16)v0; w[1] = (__bf16)v1; w[2] = (__bf16)v2; w[3] = (__bf16)v3;
          *(bf16x4*)&k_pack[idx] = w;
        }
      }
    }
  }
}

// ---------------- proj GEMM 64x128 + T1, OPERAND-SWAPPED (float4 stores) --------
__global__ __launch_bounds__(256) void gemm_proj(
    const __bf16* __restrict__ A, const __bf16* __restrict__ Bw,
    const float* __restrict__ bias, float* __restrict__ outf) {
  const int K = CDIM, N = CDIM;
  __shared__ alignas(16) __bf16 lda[64 * 64];
  __shared__ alignas(16) __bf16 ldb[128 * 64];
  const int tid = threadIdx.x;
  const int lane = tid & 63, wid = tid >> 6;
  const int hw = (int)(blockIdx.x + 8 * blockIdx.y);  // 512 blocks, 512%8==0
  const int logi = (hw & 7) * 64 + (hw >> 3);
  const int row0 = (logi / 8) * 64, col0 = (logi % 8) * 128;
  f32x4 acc[4][2] = {};

  const int srow = lane >> 3;
  const int scb = ((lane & 7) ^ (lane >> 3)) * 16;

  for (int k0 = 0; k0 < K; k0 += 64) {
#pragma unroll
    for (int j = 0; j < 2; ++j) {
      int blk = j * 4 + wid;
      gl_lds16((const char*)(A + (size_t)(row0 + blk * 8 + srow) * K + k0) + scb,
               (char*)lda + blk * 1024);
    }
#pragma unroll
    for (int j = 0; j < 4; ++j) {
      int blk = j * 4 + wid;
      gl_lds16((const char*)(Bw + (size_t)(col0 + blk * 8 + srow) * K + k0) + scb,
               (char*)ldb + blk * 1024);
    }
    __syncthreads();
#pragma unroll
    for (int kk = 0; kk < 2; ++kk) {
      const int sl = (((kk << 2) | (lane >> 4)) ^ (lane & 7)) * 16;
      bf16x8 af[4], bfr[2];
#pragma unroll
      for (int m = 0; m < 4; ++m)
        af[m] = *(const bf16x8*)((const char*)lda + (m * 16 + (lane & 15)) * 128 + sl);
#pragma unroll
      for (int n = 0; n < 2; ++n)
        bfr[n] = *(const bf16x8*)((const char*)ldb +
                                  (wid * 32 + n * 16 + (lane & 15)) * 128 + sl);
#pragma unroll
      for (int m = 0; m < 4; ++m)
#pragma unroll
        for (int n = 0; n < 2; ++n)
          acc[m][n] = __builtin_amdgcn_mfma_f32_16x16x32_bf16(bfr[n], af[m], acc[m][n], 0, 0, 0);
    }
    __syncthreads();
  }
  // swapped D: thread owns 4 consecutive output features of one token -> float4
#pragma unroll
  for (int m = 0; m < 4; ++m) {
    const int r = row0 + m * 16 + (lane & 15);  // token
#pragma unroll
    for (int n = 0; n < 2; ++n) {
      const int c0 = col0 + wid * 32 + n * 16 + (lane >> 4) * 4;  // feature
      const float4 bv = *(const float4*)&bias[c0];
      float4 o4;
      o4.x = acc[m][n][0] + bv.x;
      o4.y = acc[m][n][1] + bv.y;
      o4.z = acc[m][n][2] + bv.z;
      o4.w = acc[m][n][3] + bv.w;
      *(float4*)&outf[(size_t)r * N + c0] = o4;
    }
  }
}

// ---------------- attention: fixed-ref softmax (measured-best, FROZEN) ----------
__device__ __forceinline__ void softmax_pv(
    f32x16& s, bool domask, int lq, int hi,
    float& l_r, f32x16& o0, f32x16& o1,
    const bf16x8* va0, const bf16x8* va1) {
#pragma unroll
  for (int r = 0; r < 16; ++r) s[r] = fexp2(s[r]);
  if (domask) {
#pragma unroll
    for (int r = 0; r < 16; ++r) {
      int kof = (r & 3) + 8 * (r >> 2) + 4 * hi;
      if (kof > lq) s[r] = 0.f;
    }
  }
  l_r += tsum16(s);  // per-hi-half partial; cross-half shfl deferred to epilogue
  bf16x8 pb[2];
#pragma unroll
  for (int kh = 0; kh < 2; ++kh) {
    const int bq = kh * 8;
    unsigned w0 = cvtpk(s[bq + 0], s[bq + 1]);
    unsigned w1 = cvtpk(s[bq + 2], s[bq + 3]);
    unsigned w2 = cvtpk(s[bq + 4], s[bq + 5]);
    unsigned w3 = cvtpk(s[bq + 6], s[bq + 7]);
    permswap(w0, w2);
    permswap(w1, w3);
    union { unsigned u[4]; bf16x8 v; } pbu;
    pbu.u[0] = w0; pbu.u[1] = w1; pbu.u[2] = w2; pbu.u[3] = w3;
    pb[kh] = pbu.v;
  }
  o0 = __builtin_amdgcn_mfma_f32_32x32x16_bf16(va0[0], pb[0], o0, 0, 0, 0);
  o0 = __builtin_amdgcn_mfma_f32_32x32x16_bf16(va0[1], pb[1], o0, 0, 0, 0);
  o1 = __builtin_amdgcn_mfma_f32_32x32x16_bf16(va1[0], pb[0], o1, 0, 0, 0);
  o1 = __builtin_amdgcn_mfma_f32_32x32x16_bf16(va1[1], pb[1], o1, 0, 0, 0);
}

// ---------------- flash attention: paired chunks, PACKED coalesced loads ----------
__global__ __launch_bounds__(64) void attn_fwd(
    const __bf16* __restrict__ q_pack, const __bf16* __restrict__ k_pack,
    const __bf16* __restrict__ v_pack, __bf16* __restrict__ y_buf) {
  const int lane = threadIdx.x;
  const int lq = lane & 31;
  const int hi = lane >> 5;
  const int bh = blockIdx.x;
  const int wv = blockIdx.y;          // wv=0 (64-iter block) dispatched first
  const int b = bh >> 4, h = bh & 15;
  const int cH = 63 - wv, cL = wv;
  const float slope2 = exp2f(-0.5f * (float)(h + 1)) * 1.44269504f;
  const __bf16* qpk = q_pack + (size_t)bh * 64 * 2048;
  const __bf16* kpk = k_pack + (size_t)bh * 64 * 2048;
  const __bf16* vpk = v_pack + (size_t)bh * 64 * 2048;
  const int lo = lane * 8;  // elem offset inside each 512-elem fragment block

  bf16x8 qfH[4], qfL[4];
#pragma unroll
  for (int m = 0; m < 4; ++m) {
    qfH[m] = *(const bf16x8*)&qpk[(size_t)(cH * 4 + m) * 512 + lo];
    qfL[m] = *(const bf16x8*)&qpk[(size_t)(cL * 4 + m) * 512 + lo];
  }
  float pk_[16];
#pragma unroll
  for (int r = 0; r < 16; ++r)
    pk_[r] = slope2 * (float)((r & 3) + 8 * (r >> 2) + 4 * hi);

  f32x16 oH0 = {}, oH1 = {}, oL0 = {}, oL1 = {};
  float lH = 0.f, lL = 0.f;

  bf16x8 kf[4];
#pragma unroll
  for (int m = 0; m < 4; ++m)
    kf[m] = *(const bf16x8*)&kpk[(size_t)m * 512 + lo];

  for (int j = 0; j <= cH; ++j) {
    const int kt = j * 32;
    bf16x8 va0[2], va1[2];
#pragma unroll
    for (int kh = 0; kh < 2; ++kh) {
      va0[kh] = *(const bf16x8*)&vpk[(size_t)(j * 4 + kh * 2 + 0) * 512 + lo];
      va1[kh] = *(const bf16x8*)&vpk[(size_t)(j * 4 + kh * 2 + 1) * 512 + lo];
    }
    bf16x8 kn[4];
    const bool pre = (j < cH);
    if (pre) {
#pragma unroll
      for (int m = 0; m < 4; ++m)
        kn[m] = *(const bf16x8*)&kpk[(size_t)((j + 1) * 4 + m) * 512 + lo];
    }
    // bias as MFMA C-init: s starts at pk_ + slope2*(kt - q0)
    const float bH = slope2 * (float)(kt - cH * 32);
    f32x16 sH;
#pragma unroll
    for (int r = 0; r < 16; ++r) sH[r] = pk_[r] + bH;
#pragma unroll
    for (int m = 0; m < 4; ++m)
      sH = __builtin_amdgcn_mfma_f32_32x32x16_bf16(kf[m], qfH[m], sH, 0, 0, 0);
    const bool lact = (j <= cL);
    f32x16 sL;
    if (lact) {
      const float bL = slope2 * (float)(kt - cL * 32);
#pragma unroll
      for (int r = 0; r < 16; ++r) sL[r] = pk_[r] + bL;
#pragma unroll
      for (int m = 0; m < 4; ++m)
        sL = __builtin_amdgcn_mfma_f32_32x32x16_bf16(kf[m], qfL[m], sL, 0, 0, 0);
    }
    softmax_pv(sH, j == cH, lq, hi, lH, oH0, oH1, va0, va1);
    if (lact)
      softmax_pv(sL, j == cL, lq, hi, lL, oL0, oL1, va0, va1);
    if (pre) {
#pragma unroll
      for (int m = 0; m < 4; ++m) kf[m] = kn[m];
    }
  }
  // deferred cross-half l reduction (once)
  lH += __shfl_xor(lH, 32, 64);
  lL += __shfl_xor(lL, 32, 64);

  // normalized direct write: lane owns q-row t = c*32+lq; d = 8g+4hi+e (+32 for o1)
#pragma unroll
  for (int g2 = 0; g2 < 2; ++g2) {
    const int c = g2 ? cL : cH;
    const f32x16& a0 = g2 ? oL0 : oH0;
    const f32x16& a1 = g2 ? oL1 : oH1;
    const float inv = 1.0f / (g2 ? lL : lH);
    __bf16* yb = y_buf + ((size_t)b * TSEQ + c * 32 + lq) * CDIM + h * DH;
#pragma unroll
    for (int g = 0; g < 4; ++g) {
      bf16x4 v0, v1;
#pragma unroll
      for (int e = 0; e < 4; ++e) {
        v0[e] = (__bf16)(a0[4 * g + e] * inv);
        v1[e] = (__bf16)(a1[4 * g + e] * inv);
      }
      *(bf16x4*)&yb[8 * g + 4 * hi] = v0;
      *(bf16x4*)&yb[32 + 8 * g + 4 * hi] = v1;
    }
  }
}

extern "C" void kernel_launch(void* const* d_in, const int* in_sizes, int n_in,
                              void* d_out, int out_size, void* d_ws, size_t ws_size,
                              hipStream_t stream) {
  const float* x      = (const float*)d_in[0];
  const float* W_attn = (const float*)d_in[1];
  const float* b_attn = (const float*)d_in[2];
  const float* W_proj = (const float*)d_in[3];
  const float* b_proj = (const float*)d_in[4];
  float* out = (float*)d_out;
  char* ws = (char*)d_ws;
  const size_t MB = (size_t)1 << 20;
  __bf16* xb  = (__bf16*)(ws + 0 * MB);
  __bf16* wab = (__bf16*)(ws + 8 * MB);
  __bf16* wpb = (__bf16*)(ws + 14 * MB);
  __bf16* qpk = (__bf16*)(ws + 16 * MB);  // 8 MB packed Q frags
  __bf16* kpk = (__bf16*)(ws + 24 * MB);  // 8 MB packed K frags
  __bf16* vpk = (__bf16*)(ws + 32 * MB);  // 8 MB packed V frags
  __bf16* yb  = (__bf16*)(ws + 40 * MB);

  cvt_bf16_all<<<4096, 256, 0, stream>>>(x, W_attn, W_proj, xb, wab, wpb);

  gemm_qkv<<<dim3(24, 32), 256, 0, stream>>>(xb, wab, b_attn, qpk, kpk, vpk, 1024);
  attn_fwd<<<dim3(32, 32), 64, 0, stream>>>(qpk, kpk, vpk, yb);
  gemm_proj<<<dim3(8, 64), 256, 0, stream>>>(yb, wpb, b_proj, out);
}